// Round 1
// baseline (630.425 us; speedup 1.0000x reference)
//
#include <hip/hip_runtime.h>
#include <stdint.h>

#define HID 64

// ---------------------------------------------------------------------------
// Detect edge-index dtype: int64 (reference) vs int32 (harness may narrow).
// If int64 with values < 2^31, every odd 32-bit word (high half) is 0.
// For 1024 random int32 values in [0,100000), P(all zero) ~ 0.
__global__ void k_detect(const unsigned* __restrict__ p, unsigned* __restrict__ flag,
                         int nWords) {
  __shared__ unsigned acc;
  if (threadIdx.x == 0) acc = 0u;
  __syncthreads();
  int i = 2 * (int)threadIdx.x + 1;
  unsigned v = (i < nWords) ? p[i] : 0u;
  if (v) atomicOr(&acc, 1u);
  __syncthreads();
  if (threadIdx.x == 0) *flag = (acc == 0u) ? 1u : 0u;  // 1 => int64
}

// ---------------------------------------------------------------------------
// M_pos = W_pos @ Wp, M_neg = W_neg @ Wn  (64x64 each),
// c = b_pos @ Wp + bp + b_neg @ Wn + bn   (64)
__global__ __launch_bounds__(256) void k_prep(
    const float* __restrict__ Wpos, const float* __restrict__ Wneg,
    const float* __restrict__ Wp, const float* __restrict__ Wn,
    const float* __restrict__ bpos, const float* __restrict__ bneg,
    const float* __restrict__ bp, const float* __restrict__ bn,
    float* __restrict__ Mp, float* __restrict__ Mn, float* __restrict__ cvec) {
  int idx = blockIdx.x * 256 + threadIdx.x;  // 0..4095 over 16 blocks
  int i = idx >> 6, j = idx & 63;
  float a = 0.f, b = 0.f;
  for (int k = 0; k < 64; ++k) {
    a += Wpos[i * 64 + k] * Wp[k * 64 + j];
    b += Wneg[i * 64 + k] * Wn[k * 64 + j];
  }
  Mp[idx] = a;
  Mn[idx] = b;
  if (blockIdx.x == 0 && threadIdx.x < 64) {
    int jj = threadIdx.x;
    float acc = bp[jj] + bn[jj];
    for (int k = 0; k < 64; ++k)
      acc += bpos[k] * Wp[k * 64 + jj] + bneg[k] * Wn[k * 64 + jj];
    cvec[jj] = acc;
  }
}

// ---------------------------------------------------------------------------
// Degree count over dst (edge part only; +1 self-loop added in k_dinv).
__global__ __launch_bounds__(256) void k_deg(const void* __restrict__ ei,
                                             const unsigned* __restrict__ flag,
                                             float* __restrict__ deg, int E) {
  int e = blockIdx.x * 256 + threadIdx.x;
  if (e >= E) return;
  long long d;
  if (*flag) d = ((const long long*)ei)[(long long)E + e];
  else       d = (long long)((const int*)ei)[(long long)E + e];
  atomicAdd(&deg[(int)d], 1.0f);
}

__global__ __launch_bounds__(256) void k_dinv(float* __restrict__ degp,
                                              float* __restrict__ degn, int N) {
  int i = blockIdx.x * 256 + threadIdx.x;
  if (i < N) {
    degp[i] = rsqrtf(degp[i] + 1.0f);
    degn[i] = rsqrtf(degn[i] + 1.0f);
  }
}

// ---------------------------------------------------------------------------
// Fused LayerNorm + dual GEMM: y_pos = LN(h) @ Mp, y_neg = LN(h) @ Mn.
// Block handles 64 rows; 256 threads.
__global__ __launch_bounds__(256) void k_ln_gemm(
    const float* __restrict__ h, const float* __restrict__ gamma,
    const float* __restrict__ beta, const float* __restrict__ Mp,
    const float* __restrict__ Mn, float* __restrict__ yp, float* __restrict__ yn,
    int N) {
  __shared__ float tile[64][65];           // +1 pad: conflict-free row reads
  __shared__ __align__(16) float lMp[64][64];
  __shared__ __align__(16) float lMn[64][64];
  const int t = threadIdx.x;
  const int r0 = blockIdx.x * 64;

  // Load 64x64 h tile as float4 (coalesced), zero-fill OOB rows.
  for (int i = 0; i < 4; ++i) {
    int fi = i * 256 + t;        // float4 index in tile, 0..1023
    int row = fi >> 4;           // 16 float4 per row
    int col4 = fi & 15;
    float4 v = make_float4(0.f, 0.f, 0.f, 0.f);
    if (r0 + row < N) v = ((const float4*)h)[(size_t)(r0 + row) * 16 + col4];
    tile[row][col4 * 4 + 0] = v.x;
    tile[row][col4 * 4 + 1] = v.y;
    tile[row][col4 * 4 + 2] = v.z;
    tile[row][col4 * 4 + 3] = v.w;
  }
  // Load M matrices into LDS.
  for (int i = 0; i < 16; ++i) {
    int idx = i * 256 + t;
    ((float*)lMp)[idx] = Mp[idx];
    ((float*)lMn)[idx] = Mn[idx];
  }
  __syncthreads();

  // LayerNorm: 4 threads per row (r = t>>2, part p = t&3 covering 16 cols).
  const int r = t >> 2, p = t & 3;
  float s = 0.f, ss = 0.f;
  for (int k = 0; k < 16; ++k) {
    float v = tile[r][p * 16 + k];
    s += v;
    ss += v * v;
  }
  s += __shfl_xor(s, 1);  ss += __shfl_xor(ss, 1);
  s += __shfl_xor(s, 2);  ss += __shfl_xor(ss, 2);
  float mu = s * (1.f / 64.f);
  float var = ss * (1.f / 64.f) - mu * mu;
  float rstd = rsqrtf(var + 1e-5f);
  for (int k = 0; k < 16; ++k) {
    int c = p * 16 + k;
    float v = tile[r][c];
    tile[r][c] = (v - mu) * rstd * gamma[c] + beta[c];
  }
  __syncthreads();

  // GEMM: thread (r = t>>2) computes cols [p*16, p*16+16) for both matrices.
  float accp[16], accn[16];
#pragma unroll
  for (int j = 0; j < 16; ++j) { accp[j] = 0.f; accn[j] = 0.f; }
  for (int k = 0; k < 64; ++k) {
    float a = tile[r][k];
    const float4* mp4 = (const float4*)&lMp[k][p * 16];
    const float4* mn4 = (const float4*)&lMn[k][p * 16];
#pragma unroll
    for (int q = 0; q < 4; ++q) {
      float4 m = mp4[q];
      accp[4 * q + 0] += a * m.x;
      accp[4 * q + 1] += a * m.y;
      accp[4 * q + 2] += a * m.z;
      accp[4 * q + 3] += a * m.w;
      float4 n = mn4[q];
      accn[4 * q + 0] += a * n.x;
      accn[4 * q + 1] += a * n.y;
      accn[4 * q + 2] += a * n.z;
      accn[4 * q + 3] += a * n.w;
    }
  }
  if (r0 + r < N) {
    float4* yp4 = (float4*)(yp + (size_t)(r0 + r) * 64 + p * 16);
    float4* yn4 = (float4*)(yn + (size_t)(r0 + r) * 64 + p * 16);
#pragma unroll
    for (int q = 0; q < 4; ++q) {
      yp4[q] = make_float4(accp[4 * q], accp[4 * q + 1], accp[4 * q + 2], accp[4 * q + 3]);
      yn4[q] = make_float4(accn[4 * q], accn[4 * q + 1], accn[4 * q + 2], accn[4 * q + 3]);
    }
  }
}

// ---------------------------------------------------------------------------
// out = c + dinvp^2 * y_pos + dinvn^2 * y_neg   (self-loop terms + constants)
__global__ __launch_bounds__(256) void k_init_out(
    const float4* __restrict__ yp, const float4* __restrict__ yn,
    const float* __restrict__ dinvp, const float* __restrict__ dinvn,
    const float4* __restrict__ cvec, float4* __restrict__ out, int n4) {
  int i = blockIdx.x * 256 + threadIdx.x;
  if (i >= n4) return;
  int row = i >> 4, c4 = i & 15;
  float ap = dinvp[row]; ap *= ap;
  float an = dinvn[row]; an *= an;
  float4 a = yp[i], b = yn[i], cc = cvec[c4];
  out[i] = make_float4(cc.x + ap * a.x + an * b.x, cc.y + ap * a.y + an * b.y,
                       cc.z + ap * a.z + an * b.z, cc.w + ap * a.w + an * b.w);
}

// ---------------------------------------------------------------------------
// One wave per edge: out[dst][lane] += dinv[s]*dinv[d]*y[src][lane]
__global__ __launch_bounds__(256) void k_scatter(
    const void* __restrict__ ei, const unsigned* __restrict__ flag,
    const float* __restrict__ dinv, const float* __restrict__ y,
    float* __restrict__ out, int E) {
  const int lane = threadIdx.x & 63;
  long long e = ((long long)blockIdx.x * 256 + threadIdx.x) >> 6;
  if (e >= E) return;
  long long s, d;
  if (*flag) {
    const long long* p = (const long long*)ei;
    s = p[e];
    d = p[E + e];
  } else {
    const int* p = (const int*)ei;
    s = (long long)p[e];
    d = (long long)p[E + e];
  }
  float coef = dinv[(int)s] * dinv[(int)d];
  float v = coef * y[s * 64 + lane];
  atomicAdd(out + d * 64 + lane, v);
}

__global__ __launch_bounds__(256) void k_clip(float4* __restrict__ out, int n4) {
  int i = blockIdx.x * 256 + threadIdx.x;
  if (i >= n4) return;
  float4 v = out[i];
  v.x = fminf(fmaxf(v.x, -50.f), 50.f);
  v.y = fminf(fmaxf(v.y, -50.f), 50.f);
  v.z = fminf(fmaxf(v.z, -50.f), 50.f);
  v.w = fminf(fmaxf(v.w, -50.f), 50.f);
  out[i] = v;
}

// ---------------------------------------------------------------------------
extern "C" void kernel_launch(void* const* d_in, const int* in_sizes, int n_in,
                              void* d_out, int out_size, void* d_ws, size_t ws_size,
                              hipStream_t stream) {
  const float* h      = (const float*)d_in[1];
  const void*  ei_pos = d_in[2];
  const void*  ei_neg = d_in[3];
  const float* gamma  = (const float*)d_in[4];
  const float* beta   = (const float*)d_in[5];
  const float* W_pos  = (const float*)d_in[6];
  const float* b_pos  = (const float*)d_in[7];
  const float* W_neg  = (const float*)d_in[8];
  const float* b_neg  = (const float*)d_in[9];
  const float* Wp     = (const float*)d_in[10];
  const float* bp     = (const float*)d_in[11];
  const float* Wn     = (const float*)d_in[12];
  const float* bn     = (const float*)d_in[13];
  float* out = (float*)d_out;

  const int N = in_sizes[1] / HID;
  const int E = in_sizes[2] / 2;

  // Workspace carve-up (floats), 64-float aligned segments.
  float* ws = (float*)d_ws;
  size_t off = 0;
  auto alloc = [&](size_t nf) {
    float* p = ws + off;
    off = (off + nf + 63) & ~(size_t)63;
    return p;
  };
  float* y_pos = alloc((size_t)N * HID);
  float* y_neg = alloc((size_t)N * HID);
  float* dinvp = alloc(N);
  float* dinvn = alloc(N);
  float* Mp    = alloc(64 * 64);
  float* Mn    = alloc(64 * 64);
  float* cvec  = alloc(64);
  unsigned* flag = (unsigned*)alloc(64);

  hipMemsetAsync(dinvp, 0, sizeof(float) * N, stream);
  hipMemsetAsync(dinvn, 0, sizeof(float) * N, stream);

  k_detect<<<1, 1024, 0, stream>>>((const unsigned*)ei_pos, flag, 2 * E);
  k_prep<<<16, 256, 0, stream>>>(W_pos, W_neg, Wp, Wn, b_pos, b_neg, bp, bn, Mp, Mn, cvec);
  k_deg<<<(E + 255) / 256, 256, 0, stream>>>(ei_pos, flag, dinvp, E);
  k_deg<<<(E + 255) / 256, 256, 0, stream>>>(ei_neg, flag, dinvn, E);
  k_dinv<<<(N + 255) / 256, 256, 0, stream>>>(dinvp, dinvn, N);
  k_ln_gemm<<<(N + 63) / 64, 256, 0, stream>>>(h, gamma, beta, Mp, Mn, y_pos, y_neg, N);

  const int n4 = N * 16;
  k_init_out<<<(n4 + 255) / 256, 256, 0, stream>>>(
      (const float4*)y_pos, (const float4*)y_neg, dinvp, dinvn,
      (const float4*)cvec, (float4*)out, n4);

  const long long scatterThreads = (long long)E * 64;
  const int scatterBlocks = (int)((scatterThreads + 255) / 256);
  k_scatter<<<scatterBlocks, 256, 0, stream>>>(ei_pos, flag, dinvp, y_pos, out, E);
  k_scatter<<<scatterBlocks, 256, 0, stream>>>(ei_neg, flag, dinvn, y_neg, out, E);

  k_clip<<<(n4 + 255) / 256, 256, 0, stream>>>((float4*)out, n4);
}

// Round 2
// 401.989 us; speedup vs baseline: 1.5683x; 1.5683x over previous
//
#include <hip/hip_runtime.h>
#include <stdint.h>

#define HID 64

// ---------------------------------------------------------------------------
// Detect edge-index dtype: int64 (reference) vs int32 (harness may narrow).
// If int64 with values < 2^31, every odd 32-bit word (high half) is 0.
__global__ void k_detect(const unsigned* __restrict__ p, unsigned* __restrict__ flag,
                         int nWords) {
  __shared__ unsigned acc;
  if (threadIdx.x == 0) acc = 0u;
  __syncthreads();
  int i = 2 * (int)threadIdx.x + 1;
  unsigned v = (i < nWords) ? p[i] : 0u;
  if (v) atomicOr(&acc, 1u);
  __syncthreads();
  if (threadIdx.x == 0) *flag = (acc == 0u) ? 1u : 0u;  // 1 => int64
}

// ---------------------------------------------------------------------------
// M_pos = W_pos @ Wp, M_neg = W_neg @ Wn  (64x64 each),
// c = b_pos @ Wp + bp + b_neg @ Wn + bn   (64)
__global__ __launch_bounds__(256) void k_prep(
    const float* __restrict__ Wpos, const float* __restrict__ Wneg,
    const float* __restrict__ Wp, const float* __restrict__ Wn,
    const float* __restrict__ bpos, const float* __restrict__ bneg,
    const float* __restrict__ bp, const float* __restrict__ bn,
    float* __restrict__ Mp, float* __restrict__ Mn, float* __restrict__ cvec) {
  int idx = blockIdx.x * 256 + threadIdx.x;  // 0..4095 over 16 blocks
  int i = idx >> 6, j = idx & 63;
  float a = 0.f, b = 0.f;
  for (int k = 0; k < 64; ++k) {
    a += Wpos[i * 64 + k] * Wp[k * 64 + j];
    b += Wneg[i * 64 + k] * Wn[k * 64 + j];
  }
  Mp[idx] = a;
  Mn[idx] = b;
  if (blockIdx.x == 0 && threadIdx.x < 64) {
    int jj = threadIdx.x;
    float acc = bp[jj] + bn[jj];
    for (int k = 0; k < 64; ++k)
      acc += bpos[k] * Wp[k * 64 + jj] + bneg[k] * Wn[k * 64 + jj];
    cvec[jj] = acc;
  }
}

// ---------------------------------------------------------------------------
// u32 degree histogram over dst (fast path).
__global__ __launch_bounds__(256) void k_degu(const void* __restrict__ ei,
                                              const unsigned* __restrict__ flag,
                                              unsigned* __restrict__ deg, int E) {
  int e = blockIdx.x * 256 + threadIdx.x;
  if (e >= E) return;
  long long d;
  if (*flag) d = ((const long long*)ei)[(long long)E + e];
  else       d = (long long)((const int*)ei)[(long long)E + e];
  atomicAdd(&deg[(int)d], 1u);
}

// float degree histogram (fallback path).
__global__ __launch_bounds__(256) void k_deg(const void* __restrict__ ei,
                                             const unsigned* __restrict__ flag,
                                             float* __restrict__ deg, int E) {
  int e = blockIdx.x * 256 + threadIdx.x;
  if (e >= E) return;
  long long d;
  if (*flag) d = ((const long long*)ei)[(long long)E + e];
  else       d = (long long)((const int*)ei)[(long long)E + e];
  atomicAdd(&deg[(int)d], 1.0f);
}

__global__ __launch_bounds__(256) void k_dinv(float* __restrict__ degp,
                                              float* __restrict__ degn, int N) {
  int i = blockIdx.x * 256 + threadIdx.x;
  if (i < N) {
    degp[i] = rsqrtf(degp[i] + 1.0f);
    degn[i] = rsqrtf(degn[i] + 1.0f);
  }
}

// ---------------------------------------------------------------------------
// Scan stage 1: per-block sums of deg.
__global__ __launch_bounds__(256) void k_blocksum(const unsigned* __restrict__ deg,
                                                  unsigned* __restrict__ bsum, int N) {
  __shared__ unsigned sh[256];
  int t = threadIdx.x;
  int i = blockIdx.x * 256 + t;
  sh[t] = (i < N) ? deg[i] : 0u;
  __syncthreads();
  for (int o = 128; o > 0; o >>= 1) {
    if (t < o) sh[t] += sh[t + o];
    __syncthreads();
  }
  if (t == 0) bsum[blockIdx.x] = sh[0];
}

// Scan stage 2: single-block exclusive scan of block sums (in place).
__global__ __launch_bounds__(256) void k_scanp(unsigned* __restrict__ bsum, int nb) {
  __shared__ unsigned sh[256];
  __shared__ unsigned carry;
  int t = threadIdx.x;
  if (t == 0) carry = 0u;
  __syncthreads();
  for (int base = 0; base < nb; base += 256) {
    unsigned v = (base + t < nb) ? bsum[base + t] : 0u;
    sh[t] = v;
    __syncthreads();
    for (int o = 1; o < 256; o <<= 1) {
      unsigned x = (t >= o) ? sh[t - o] : 0u;
      __syncthreads();
      sh[t] += x;
      __syncthreads();
    }
    unsigned incl = sh[t];
    unsigned tot = sh[255];
    unsigned excl = incl - v + carry;
    if (base + t < nb) bsum[base + t] = excl;
    __syncthreads();
    if (t == 0) carry += tot;
    __syncthreads();
  }
}

// Scan stage 3: per-element exclusive scan -> offs; deg array becomes the fill
// cursor (= offs); also computes dinv = rsqrt(deg+1).
__global__ __launch_bounds__(256) void k_offs(unsigned* __restrict__ deg,
                                              unsigned* __restrict__ offs,
                                              const unsigned* __restrict__ bscan,
                                              float* __restrict__ dinv, int N, int E) {
  __shared__ unsigned sh[256];
  int t = threadIdx.x;
  int i = blockIdx.x * 256 + t;
  unsigned v = (i < N) ? deg[i] : 0u;
  sh[t] = v;
  __syncthreads();
  for (int o = 1; o < 256; o <<= 1) {
    unsigned x = (t >= o) ? sh[t - o] : 0u;
    __syncthreads();
    sh[t] += x;
    __syncthreads();
  }
  unsigned excl = sh[t] - v + bscan[blockIdx.x];
  if (i < N) {
    offs[i] = excl;
    deg[i] = excl;  // cursor for k_fill
    dinv[i] = rsqrtf((float)v + 1.0f);
  }
  if (blockIdx.x == 0 && t == 0) offs[N] = (unsigned)E;
}

// Fill CSR: csr[cursor[dst]++] = src.
__global__ __launch_bounds__(256) void k_fill(const void* __restrict__ ei,
                                              const unsigned* __restrict__ flag,
                                              unsigned* __restrict__ cursor,
                                              unsigned* __restrict__ csr, int E) {
  int e = blockIdx.x * 256 + threadIdx.x;
  if (e >= E) return;
  long long s, d;
  if (*flag) {
    const long long* p = (const long long*)ei;
    s = p[e]; d = p[E + e];
  } else {
    const int* p = (const int*)ei;
    s = (long long)p[e]; d = (long long)p[E + e];
  }
  unsigned pos = atomicAdd(&cursor[(int)d], 1u);
  csr[pos] = (unsigned)s;
}

// ---------------------------------------------------------------------------
// Fused LayerNorm + dual GEMM, epilogue scales by dinv[row]:
//   y_pos = dinvp[r] * (LN(h) @ Mp),  y_neg = dinvn[r] * (LN(h) @ Mn)
__global__ __launch_bounds__(256) void k_ln_gemm(
    const float* __restrict__ h, const float* __restrict__ gamma,
    const float* __restrict__ beta, const float* __restrict__ Mp,
    const float* __restrict__ Mn, const float* __restrict__ dinvp,
    const float* __restrict__ dinvn, float* __restrict__ yp,
    float* __restrict__ yn, int N) {
  __shared__ float tile[64][65];
  __shared__ __align__(16) float lMp[64][64];
  __shared__ __align__(16) float lMn[64][64];
  const int t = threadIdx.x;
  const int r0 = blockIdx.x * 64;

  for (int i = 0; i < 4; ++i) {
    int fi = i * 256 + t;
    int row = fi >> 4;
    int col4 = fi & 15;
    float4 v = make_float4(0.f, 0.f, 0.f, 0.f);
    if (r0 + row < N) v = ((const float4*)h)[(size_t)(r0 + row) * 16 + col4];
    tile[row][col4 * 4 + 0] = v.x;
    tile[row][col4 * 4 + 1] = v.y;
    tile[row][col4 * 4 + 2] = v.z;
    tile[row][col4 * 4 + 3] = v.w;
  }
  for (int i = 0; i < 16; ++i) {
    int idx = i * 256 + t;
    ((float*)lMp)[idx] = Mp[idx];
    ((float*)lMn)[idx] = Mn[idx];
  }
  __syncthreads();

  const int r = t >> 2, p = t & 3;
  float s = 0.f, ss = 0.f;
  for (int k = 0; k < 16; ++k) {
    float v = tile[r][p * 16 + k];
    s += v;
    ss += v * v;
  }
  s += __shfl_xor(s, 1);  ss += __shfl_xor(ss, 1);
  s += __shfl_xor(s, 2);  ss += __shfl_xor(ss, 2);
  float mu = s * (1.f / 64.f);
  float var = ss * (1.f / 64.f) - mu * mu;
  float rstd = rsqrtf(var + 1e-5f);
  for (int k = 0; k < 16; ++k) {
    int c = p * 16 + k;
    float v = tile[r][c];
    tile[r][c] = (v - mu) * rstd * gamma[c] + beta[c];
  }
  __syncthreads();

  float accp[16], accn[16];
#pragma unroll
  for (int j = 0; j < 16; ++j) { accp[j] = 0.f; accn[j] = 0.f; }
  for (int k = 0; k < 64; ++k) {
    float a = tile[r][k];
    const float4* mp4 = (const float4*)&lMp[k][p * 16];
    const float4* mn4 = (const float4*)&lMn[k][p * 16];
#pragma unroll
    for (int q = 0; q < 4; ++q) {
      float4 m = mp4[q];
      accp[4 * q + 0] += a * m.x;
      accp[4 * q + 1] += a * m.y;
      accp[4 * q + 2] += a * m.z;
      accp[4 * q + 3] += a * m.w;
      float4 n = mn4[q];
      accn[4 * q + 0] += a * n.x;
      accn[4 * q + 1] += a * n.y;
      accn[4 * q + 2] += a * n.z;
      accn[4 * q + 3] += a * n.w;
    }
  }
  if (r0 + r < N) {
    float sp = dinvp[r0 + r], sn = dinvn[r0 + r];
    float4* yp4 = (float4*)(yp + (size_t)(r0 + r) * 64 + p * 16);
    float4* yn4 = (float4*)(yn + (size_t)(r0 + r) * 64 + p * 16);
#pragma unroll
    for (int q = 0; q < 4; ++q) {
      yp4[q] = make_float4(sp * accp[4 * q], sp * accp[4 * q + 1],
                           sp * accp[4 * q + 2], sp * accp[4 * q + 3]);
      yn4[q] = make_float4(sn * accn[4 * q], sn * accn[4 * q + 1],
                           sn * accn[4 * q + 2], sn * accn[4 * q + 3]);
    }
  }
}

// ---------------------------------------------------------------------------
// Gather: one wave per dst node. acc = y_scaled[d] + sum_{s in N(d)} y_scaled[s];
// out[d] = clip(c + dinvp[d]*acc_p + dinvn[d]*acc_n).
__global__ __launch_bounds__(256) void k_gather(
    const unsigned* __restrict__ offsp, const unsigned* __restrict__ csrp,
    const float* __restrict__ dinvp, const unsigned* __restrict__ offsn,
    const unsigned* __restrict__ csrn, const float* __restrict__ dinvn,
    const float* __restrict__ yp, const float* __restrict__ yn,
    const float* __restrict__ cvec, float* __restrict__ out, int N) {
  const int lane = threadIdx.x & 63;
  const int d = (int)(((long long)blockIdx.x * 256 + threadIdx.x) >> 6);
  if (d >= N) return;

  float accp = yp[(size_t)d * 64 + lane];  // self-loop (scaled)
  {
    unsigned beg = offsp[d], end = offsp[d + 1];
    float a0 = 0.f, a1 = 0.f;
    for (unsigned base = beg; base < end; base += 64u) {
      int m = (int)min(64u, end - base);
      int idx = (base + (unsigned)lane < end) ? (int)csrp[base + lane] : 0;
      int j = 0;
      for (; j + 1 < m; j += 2) {
        int s0 = __shfl(idx, j);
        int s1 = __shfl(idx, j + 1);
        a0 += yp[(size_t)s0 * 64 + lane];
        a1 += yp[(size_t)s1 * 64 + lane];
      }
      if (j < m) {
        int s0 = __shfl(idx, j);
        a0 += yp[(size_t)s0 * 64 + lane];
      }
    }
    accp += a0 + a1;
  }
  float accn = yn[(size_t)d * 64 + lane];
  {
    unsigned beg = offsn[d], end = offsn[d + 1];
    float a0 = 0.f, a1 = 0.f;
    for (unsigned base = beg; base < end; base += 64u) {
      int m = (int)min(64u, end - base);
      int idx = (base + (unsigned)lane < end) ? (int)csrn[base + lane] : 0;
      int j = 0;
      for (; j + 1 < m; j += 2) {
        int s0 = __shfl(idx, j);
        int s1 = __shfl(idx, j + 1);
        a0 += yn[(size_t)s0 * 64 + lane];
        a1 += yn[(size_t)s1 * 64 + lane];
      }
      if (j < m) {
        int s0 = __shfl(idx, j);
        a0 += yn[(size_t)s0 * 64 + lane];
      }
    }
    accn += a0 + a1;
  }
  float v = cvec[lane] + dinvp[d] * accp + dinvn[d] * accn;
  out[(size_t)d * 64 + lane] = fminf(fmaxf(v, -50.f), 50.f);
}

// ---------------------------------------------------------------------------
// Fallback path (atomics), y pre-scaled by dinv[src]:
// out = c + dinvp[d]*yp[d] + dinvn[d]*yn[d]  then scatter adds dinv[d]*y[s].
__global__ __launch_bounds__(256) void k_init_out(
    const float4* __restrict__ yp, const float4* __restrict__ yn,
    const float* __restrict__ dinvp, const float* __restrict__ dinvn,
    const float4* __restrict__ cvec, float4* __restrict__ out, int n4) {
  int i = blockIdx.x * 256 + threadIdx.x;
  if (i >= n4) return;
  int row = i >> 4, c4 = i & 15;
  float ap = dinvp[row];
  float an = dinvn[row];
  float4 a = yp[i], b = yn[i], cc = cvec[c4];
  out[i] = make_float4(cc.x + ap * a.x + an * b.x, cc.y + ap * a.y + an * b.y,
                       cc.z + ap * a.z + an * b.z, cc.w + ap * a.w + an * b.w);
}

__global__ __launch_bounds__(256) void k_scatter(
    const void* __restrict__ ei, const unsigned* __restrict__ flag,
    const float* __restrict__ dinv, const float* __restrict__ y,
    float* __restrict__ out, int E) {
  const int lane = threadIdx.x & 63;
  long long e = ((long long)blockIdx.x * 256 + threadIdx.x) >> 6;
  if (e >= E) return;
  long long s, d;
  if (*flag) {
    const long long* p = (const long long*)ei;
    s = p[e]; d = p[E + e];
  } else {
    const int* p = (const int*)ei;
    s = (long long)p[e]; d = (long long)p[E + e];
  }
  float v = dinv[(int)d] * y[s * 64 + lane];
  atomicAdd(out + d * 64 + lane, v);
}

__global__ __launch_bounds__(256) void k_clip(float4* __restrict__ out, int n4) {
  int i = blockIdx.x * 256 + threadIdx.x;
  if (i >= n4) return;
  float4 v = out[i];
  v.x = fminf(fmaxf(v.x, -50.f), 50.f);
  v.y = fminf(fmaxf(v.y, -50.f), 50.f);
  v.z = fminf(fmaxf(v.z, -50.f), 50.f);
  v.w = fminf(fmaxf(v.w, -50.f), 50.f);
  out[i] = v;
}

// ---------------------------------------------------------------------------
extern "C" void kernel_launch(void* const* d_in, const int* in_sizes, int n_in,
                              void* d_out, int out_size, void* d_ws, size_t ws_size,
                              hipStream_t stream) {
  const float* h      = (const float*)d_in[1];
  const void*  ei_pos = d_in[2];
  const void*  ei_neg = d_in[3];
  const float* gamma  = (const float*)d_in[4];
  const float* beta   = (const float*)d_in[5];
  const float* W_pos  = (const float*)d_in[6];
  const float* b_pos  = (const float*)d_in[7];
  const float* W_neg  = (const float*)d_in[8];
  const float* b_neg  = (const float*)d_in[9];
  const float* Wp     = (const float*)d_in[10];
  const float* bp     = (const float*)d_in[11];
  const float* Wn     = (const float*)d_in[12];
  const float* bn     = (const float*)d_in[13];
  float* out = (float*)d_out;

  const int N = in_sizes[1] / HID;
  const int E = in_sizes[2] / 2;
  const int nb = (N + 255) / 256;

  float* ws = (float*)d_ws;
  size_t off = 0;
  auto alloc = [&](size_t nf) {
    float* p = ws + off;
    off = (off + nf + 63) & ~(size_t)63;
    return p;
  };
  // Common arrays.
  float* y_pos = alloc((size_t)N * HID);
  float* y_neg = alloc((size_t)N * HID);
  float* dinvp = alloc(N);
  float* dinvn = alloc(N);
  float* Mp    = alloc(64 * 64);
  float* Mn    = alloc(64 * 64);
  float* cvec  = alloc(64);
  unsigned* flag = (unsigned*)alloc(64);
  // Fast-path (CSR) arrays.
  unsigned* degp  = (unsigned*)alloc(N);       // becomes fill cursor
  unsigned* degn  = (unsigned*)alloc(N);
  unsigned* offsp = (unsigned*)alloc(N + 1);
  unsigned* offsn = (unsigned*)alloc(N + 1);
  unsigned* csrp  = (unsigned*)alloc(E);
  unsigned* csrn  = (unsigned*)alloc(E);
  unsigned* bsump = (unsigned*)alloc(nb);
  unsigned* bsumn = (unsigned*)alloc(nb);
  const bool fast = off * sizeof(float) <= ws_size;

  k_detect<<<1, 1024, 0, stream>>>((const unsigned*)ei_pos, flag, 2 * E);
  k_prep<<<16, 256, 0, stream>>>(W_pos, W_neg, Wp, Wn, b_pos, b_neg, bp, bn, Mp, Mn, cvec);

  const int eb = (E + 255) / 256;
  const int n4 = N * 16;

  if (fast) {
    hipMemsetAsync(degp, 0, sizeof(unsigned) * N, stream);
    hipMemsetAsync(degn, 0, sizeof(unsigned) * N, stream);
    k_degu<<<eb, 256, 0, stream>>>(ei_pos, flag, degp, E);
    k_degu<<<eb, 256, 0, stream>>>(ei_neg, flag, degn, E);
    k_blocksum<<<nb, 256, 0, stream>>>(degp, bsump, N);
    k_blocksum<<<nb, 256, 0, stream>>>(degn, bsumn, N);
    k_scanp<<<1, 256, 0, stream>>>(bsump, nb);
    k_scanp<<<1, 256, 0, stream>>>(bsumn, nb);
    k_offs<<<nb, 256, 0, stream>>>(degp, offsp, bsump, dinvp, N, E);
    k_offs<<<nb, 256, 0, stream>>>(degn, offsn, bsumn, dinvn, N, E);
    k_fill<<<eb, 256, 0, stream>>>(ei_pos, flag, degp, csrp, E);
    k_fill<<<eb, 256, 0, stream>>>(ei_neg, flag, degn, csrn, E);
    k_ln_gemm<<<(N + 63) / 64, 256, 0, stream>>>(h, gamma, beta, Mp, Mn, dinvp, dinvn,
                                                 y_pos, y_neg, N);
    const long long gthreads = (long long)N * 64;
    k_gather<<<(int)((gthreads + 255) / 256), 256, 0, stream>>>(
        offsp, csrp, dinvp, offsn, csrn, dinvn, y_pos, y_neg, cvec, out, N);
  } else {
    hipMemsetAsync(dinvp, 0, sizeof(float) * N, stream);
    hipMemsetAsync(dinvn, 0, sizeof(float) * N, stream);
    k_deg<<<eb, 256, 0, stream>>>(ei_pos, flag, dinvp, E);
    k_deg<<<eb, 256, 0, stream>>>(ei_neg, flag, dinvn, E);
    k_dinv<<<(N + 255) / 256, 256, 0, stream>>>(dinvp, dinvn, N);
    k_ln_gemm<<<(N + 63) / 64, 256, 0, stream>>>(h, gamma, beta, Mp, Mn, dinvp, dinvn,
                                                 y_pos, y_neg, N);
    k_init_out<<<(n4 + 255) / 256, 256, 0, stream>>>(
        (const float4*)y_pos, (const float4*)y_neg, dinvp, dinvn,
        (const float4*)cvec, (float4*)out, n4);
    const long long st = (long long)E * 64;
    const int sb = (int)((st + 255) / 256);
    k_scatter<<<sb, 256, 0, stream>>>(ei_pos, flag, dinvp, y_pos, out, E);
    k_scatter<<<sb, 256, 0, stream>>>(ei_neg, flag, dinvn, y_neg, out, E);
    k_clip<<<(n4 + 255) / 256, 256, 0, stream>>>((float4*)out, n4);
  }
}

// Round 3
// 400.033 us; speedup vs baseline: 1.5759x; 1.0049x over previous
//
#include <hip/hip_runtime.h>
#include <stdint.h>

#define HID 64

// ---------------------------------------------------------------------------
// bf16 helpers (RTNE pack, cheap unpack). Values are finite (clipped math).
__device__ inline float bf2f(unsigned short u) {
  return __uint_as_float(((unsigned)u) << 16);
}
__device__ inline unsigned short f2bf(float f) {
  unsigned u = __float_as_uint(f);
  unsigned r = u + 0x7FFFu + ((u >> 16) & 1u);
  return (unsigned short)(r >> 16);
}

// ---------------------------------------------------------------------------
// Detect edge-index dtype: int64 (reference) vs int32. If int64 with values
// < 2^31, every odd 32-bit word (high half) is 0.
__global__ void k_detect(const unsigned* __restrict__ p, unsigned* __restrict__ flag,
                         int nWords) {
  __shared__ unsigned acc;
  if (threadIdx.x == 0) acc = 0u;
  __syncthreads();
  int i = 2 * (int)threadIdx.x + 1;
  unsigned v = (i < nWords) ? p[i] : 0u;
  if (v) atomicOr(&acc, 1u);
  __syncthreads();
  if (threadIdx.x == 0) *flag = (acc == 0u) ? 1u : 0u;  // 1 => int64
}

// ---------------------------------------------------------------------------
// M_pos = W_pos @ Wp, M_neg = W_neg @ Wn, c = b_pos@Wp + bp + b_neg@Wn + bn
__global__ __launch_bounds__(256) void k_prep(
    const float* __restrict__ Wpos, const float* __restrict__ Wneg,
    const float* __restrict__ Wp, const float* __restrict__ Wn,
    const float* __restrict__ bpos, const float* __restrict__ bneg,
    const float* __restrict__ bp, const float* __restrict__ bn,
    float* __restrict__ Mp, float* __restrict__ Mn, float* __restrict__ cvec) {
  int idx = blockIdx.x * 256 + threadIdx.x;
  int i = idx >> 6, j = idx & 63;
  float a = 0.f, b = 0.f;
  for (int k = 0; k < 64; ++k) {
    a += Wpos[i * 64 + k] * Wp[k * 64 + j];
    b += Wneg[i * 64 + k] * Wn[k * 64 + j];
  }
  Mp[idx] = a;
  Mn[idx] = b;
  if (blockIdx.x == 0 && threadIdx.x < 64) {
    int jj = threadIdx.x;
    float acc = bp[jj] + bn[jj];
    for (int k = 0; k < 64; ++k)
      acc += bpos[k] * Wp[k * 64 + jj] + bneg[k] * Wn[k * 64 + jj];
    cvec[jj] = acc;
  }
}

// ---------------------------------------------------------------------------
// Merged degree histogram over dst for both edge sets. deg = [degp | degn].
__global__ __launch_bounds__(256) void k_degu2(
    const void* __restrict__ eip, const void* __restrict__ ein,
    const unsigned* __restrict__ flag, unsigned* __restrict__ deg,
    int Ep, int En, int N) {
  long long e = (long long)blockIdx.x * 256 + threadIdx.x;
  if (e >= (long long)Ep + En) return;
  int seg = e >= Ep;
  long long ee = seg ? e - Ep : e;
  const void* ei = seg ? ein : eip;
  long long Ecur = seg ? En : Ep;
  long long d;
  if (*flag) d = ((const long long*)ei)[Ecur + ee];
  else       d = (long long)((const int*)ei)[Ecur + ee];
  atomicAdd(&deg[(long long)seg * N + (int)d], 1u);
}

// Scan stage 1: per-block sums over the combined deg array (segmented by nb).
__global__ __launch_bounds__(256) void k_blocksum2(const unsigned* __restrict__ deg,
                                                   unsigned* __restrict__ bsum,
                                                   int N, int nb) {
  __shared__ unsigned sh[256];
  int b = blockIdx.x;
  int seg = b >= nb;
  int bb = b - seg * nb;
  int t = threadIdx.x;
  int i = bb * 256 + t;
  sh[t] = (i < N) ? deg[(long long)seg * N + i] : 0u;
  __syncthreads();
  for (int o = 128; o > 0; o >>= 1) {
    if (t < o) sh[t] += sh[t + o];
    __syncthreads();
  }
  if (t == 0) bsum[b] = sh[0];
}

// Scan stage 2: grid=2; each block exclusive-scans its segment of bsum.
__global__ __launch_bounds__(256) void k_scanp2(unsigned* __restrict__ bsum, int nb) {
  __shared__ unsigned sh[256];
  __shared__ unsigned carry;
  unsigned* seg = bsum + (long long)blockIdx.x * nb;
  int t = threadIdx.x;
  if (t == 0) carry = 0u;
  __syncthreads();
  for (int base = 0; base < nb; base += 256) {
    unsigned v = (base + t < nb) ? seg[base + t] : 0u;
    sh[t] = v;
    __syncthreads();
    for (int o = 1; o < 256; o <<= 1) {
      unsigned x = (t >= o) ? sh[t - o] : 0u;
      __syncthreads();
      sh[t] += x;
      __syncthreads();
    }
    unsigned incl = sh[t];
    unsigned tot = sh[255];
    unsigned excl = incl - v + carry;
    if (base + t < nb) seg[base + t] = excl;
    __syncthreads();
    if (t == 0) carry += tot;
    __syncthreads();
  }
}

// Scan stage 3: per-element exclusive scan -> offs; deg becomes fill cursor;
// dinv = rsqrt(deg+1).
__global__ __launch_bounds__(256) void k_offs2(
    unsigned* __restrict__ deg, unsigned* __restrict__ offsp,
    unsigned* __restrict__ offsn, const unsigned* __restrict__ bscan,
    float* __restrict__ dinvp, float* __restrict__ dinvn,
    int N, int nb, int Ep, int En) {
  __shared__ unsigned sh[256];
  int b = blockIdx.x;
  int seg = b >= nb;
  int bb = b - seg * nb;
  unsigned* offs = seg ? offsn : offsp;
  float* dinv = seg ? dinvn : dinvp;
  int E = seg ? En : Ep;
  int t = threadIdx.x;
  int i = bb * 256 + t;
  unsigned v = (i < N) ? deg[(long long)seg * N + i] : 0u;
  sh[t] = v;
  __syncthreads();
  for (int o = 1; o < 256; o <<= 1) {
    unsigned x = (t >= o) ? sh[t - o] : 0u;
    __syncthreads();
    sh[t] += x;
    __syncthreads();
  }
  unsigned excl = sh[t] - v + bscan[b];
  if (i < N) {
    offs[i] = excl;
    deg[(long long)seg * N + i] = excl;  // cursor for k_fill2
    dinv[i] = rsqrtf((float)v + 1.0f);
  }
  if (bb == 0 && t == 0) offs[N] = (unsigned)E;
}

// Fill both CSRs: csr[cursor[dst]++] = src.
__global__ __launch_bounds__(256) void k_fill2(
    const void* __restrict__ eip, const void* __restrict__ ein,
    const unsigned* __restrict__ flag, unsigned* __restrict__ deg,
    unsigned* __restrict__ csrp, unsigned* __restrict__ csrn,
    int Ep, int En, int N) {
  long long e = (long long)blockIdx.x * 256 + threadIdx.x;
  if (e >= (long long)Ep + En) return;
  int seg = e >= Ep;
  long long ee = seg ? e - Ep : e;
  const void* ei = seg ? ein : eip;
  long long Ecur = seg ? En : Ep;
  unsigned* csr = seg ? csrn : csrp;
  long long s, d;
  if (*flag) {
    const long long* p = (const long long*)ei;
    s = p[ee]; d = p[Ecur + ee];
  } else {
    const int* p = (const int*)ei;
    s = (long long)p[ee]; d = (long long)p[Ecur + ee];
  }
  unsigned pos = atomicAdd(&deg[(long long)seg * N + (int)d], 1u);
  csr[pos] = (unsigned)s;
}

// ---------------------------------------------------------------------------
// Fused LayerNorm + dual GEMM, epilogue scales by dinv[row], stores bf16:
//   y_pos = bf16(dinvp[r] * (LN(h) @ Mp)), y_neg likewise.
__global__ __launch_bounds__(256) void k_ln_gemm(
    const float* __restrict__ h, const float* __restrict__ gamma,
    const float* __restrict__ beta, const float* __restrict__ Mp,
    const float* __restrict__ Mn, const float* __restrict__ dinvp,
    const float* __restrict__ dinvn, unsigned short* __restrict__ yp,
    unsigned short* __restrict__ yn, int N) {
  __shared__ float tile[64][65];
  __shared__ __align__(16) float lMp[64][64];
  __shared__ __align__(16) float lMn[64][64];
  const int t = threadIdx.x;
  const int r0 = blockIdx.x * 64;

  for (int i = 0; i < 4; ++i) {
    int fi = i * 256 + t;
    int row = fi >> 4;
    int col4 = fi & 15;
    float4 v = make_float4(0.f, 0.f, 0.f, 0.f);
    if (r0 + row < N) v = ((const float4*)h)[(size_t)(r0 + row) * 16 + col4];
    tile[row][col4 * 4 + 0] = v.x;
    tile[row][col4 * 4 + 1] = v.y;
    tile[row][col4 * 4 + 2] = v.z;
    tile[row][col4 * 4 + 3] = v.w;
  }
  for (int i = 0; i < 16; ++i) {
    int idx = i * 256 + t;
    ((float*)lMp)[idx] = Mp[idx];
    ((float*)lMn)[idx] = Mn[idx];
  }
  __syncthreads();

  const int r = t >> 2, p = t & 3;
  float s = 0.f, ss = 0.f;
  for (int k = 0; k < 16; ++k) {
    float v = tile[r][p * 16 + k];
    s += v;
    ss += v * v;
  }
  s += __shfl_xor(s, 1);  ss += __shfl_xor(ss, 1);
  s += __shfl_xor(s, 2);  ss += __shfl_xor(ss, 2);
  float mu = s * (1.f / 64.f);
  float var = ss * (1.f / 64.f) - mu * mu;
  float rstd = rsqrtf(var + 1e-5f);
  for (int k = 0; k < 16; ++k) {
    int c = p * 16 + k;
    float v = tile[r][c];
    tile[r][c] = (v - mu) * rstd * gamma[c] + beta[c];
  }
  __syncthreads();

  float accp[16], accn[16];
#pragma unroll
  for (int j = 0; j < 16; ++j) { accp[j] = 0.f; accn[j] = 0.f; }
  for (int k = 0; k < 64; ++k) {
    float a = tile[r][k];
    const float4* mp4 = (const float4*)&lMp[k][p * 16];
    const float4* mn4 = (const float4*)&lMn[k][p * 16];
#pragma unroll
    for (int q = 0; q < 4; ++q) {
      float4 m = mp4[q];
      accp[4 * q + 0] += a * m.x;
      accp[4 * q + 1] += a * m.y;
      accp[4 * q + 2] += a * m.z;
      accp[4 * q + 3] += a * m.w;
      float4 n = mn4[q];
      accn[4 * q + 0] += a * n.x;
      accn[4 * q + 1] += a * n.y;
      accn[4 * q + 2] += a * n.z;
      accn[4 * q + 3] += a * n.w;
    }
  }
  if (r0 + r < N) {
    float sp = dinvp[r0 + r], sn = dinvn[r0 + r];
    unsigned up[8], un[8];
#pragma unroll
    for (int q = 0; q < 8; ++q) {
      up[q] = (unsigned)f2bf(sp * accp[2 * q]) |
              ((unsigned)f2bf(sp * accp[2 * q + 1]) << 16);
      un[q] = (unsigned)f2bf(sn * accn[2 * q]) |
              ((unsigned)f2bf(sn * accn[2 * q + 1]) << 16);
    }
    uint4* yp4 = (uint4*)(yp + (size_t)(r0 + r) * 64 + p * 16);
    uint4* yn4 = (uint4*)(yn + (size_t)(r0 + r) * 64 + p * 16);
    yp4[0] = make_uint4(up[0], up[1], up[2], up[3]);
    yp4[1] = make_uint4(up[4], up[5], up[6], up[7]);
    yn4[0] = make_uint4(un[0], un[1], un[2], un[3]);
    yn4[1] = make_uint4(un[4], un[5], un[6], un[7]);
  }
}

// ---------------------------------------------------------------------------
// Gather: one wave per dst node, bf16 y rows (128 B each).
__global__ __launch_bounds__(256) void k_gather(
    const unsigned* __restrict__ offsp, const unsigned* __restrict__ csrp,
    const float* __restrict__ dinvp, const unsigned* __restrict__ offsn,
    const unsigned* __restrict__ csrn, const float* __restrict__ dinvn,
    const unsigned short* __restrict__ yp, const unsigned short* __restrict__ yn,
    const float* __restrict__ cvec, float* __restrict__ out, int N) {
  const int lane = threadIdx.x & 63;
  const int d = (int)(((long long)blockIdx.x * 256 + threadIdx.x) >> 6);
  if (d >= N) return;

  float accp = bf2f(yp[(size_t)d * 64 + lane]);  // self-loop (scaled)
  {
    unsigned beg = offsp[d], end = offsp[d + 1];
    float a0 = 0.f, a1 = 0.f;
    for (unsigned base = beg; base < end; base += 64u) {
      int m = (int)min(64u, end - base);
      int idx = (base + (unsigned)lane < end) ? (int)csrp[base + lane] : 0;
      int j = 0;
      for (; j + 1 < m; j += 2) {
        int s0 = __shfl(idx, j);
        int s1 = __shfl(idx, j + 1);
        a0 += bf2f(yp[(size_t)s0 * 64 + lane]);
        a1 += bf2f(yp[(size_t)s1 * 64 + lane]);
      }
      if (j < m) {
        int s0 = __shfl(idx, j);
        a0 += bf2f(yp[(size_t)s0 * 64 + lane]);
      }
    }
    accp += a0 + a1;
  }
  float accn = bf2f(yn[(size_t)d * 64 + lane]);
  {
    unsigned beg = offsn[d], end = offsn[d + 1];
    float a0 = 0.f, a1 = 0.f;
    for (unsigned base = beg; base < end; base += 64u) {
      int m = (int)min(64u, end - base);
      int idx = (base + (unsigned)lane < end) ? (int)csrn[base + lane] : 0;
      int j = 0;
      for (; j + 1 < m; j += 2) {
        int s0 = __shfl(idx, j);
        int s1 = __shfl(idx, j + 1);
        a0 += bf2f(yn[(size_t)s0 * 64 + lane]);
        a1 += bf2f(yn[(size_t)s1 * 64 + lane]);
      }
      if (j < m) {
        int s0 = __shfl(idx, j);
        a0 += bf2f(yn[(size_t)s0 * 64 + lane]);
      }
    }
    accn += a0 + a1;
  }
  float v = cvec[lane] + dinvp[d] * accp + dinvn[d] * accn;
  out[(size_t)d * 64 + lane] = fminf(fmaxf(v, -50.f), 50.f);
}

// ---------------------------------------------------------------------------
// Fallback path (atomics), bf16 y pre-scaled by dinv[src].
__global__ __launch_bounds__(256) void k_deg(const void* __restrict__ ei,
                                             const unsigned* __restrict__ flag,
                                             float* __restrict__ deg, int E) {
  int e = blockIdx.x * 256 + threadIdx.x;
  if (e >= E) return;
  long long d;
  if (*flag) d = ((const long long*)ei)[(long long)E + e];
  else       d = (long long)((const int*)ei)[(long long)E + e];
  atomicAdd(&deg[(int)d], 1.0f);
}

__global__ __launch_bounds__(256) void k_dinv(float* __restrict__ degp,
                                              float* __restrict__ degn, int N) {
  int i = blockIdx.x * 256 + threadIdx.x;
  if (i < N) {
    degp[i] = rsqrtf(degp[i] + 1.0f);
    degn[i] = rsqrtf(degn[i] + 1.0f);
  }
}

__global__ __launch_bounds__(256) void k_init_out(
    const unsigned short* __restrict__ yp, const unsigned short* __restrict__ yn,
    const float* __restrict__ dinvp, const float* __restrict__ dinvn,
    const float* __restrict__ cvec, float* __restrict__ out, long long n) {
  long long i = (long long)blockIdx.x * 256 + threadIdx.x;
  if (i >= n) return;
  int row = (int)(i >> 6), col = (int)(i & 63);
  out[i] = cvec[col] + dinvp[row] * bf2f(yp[i]) + dinvn[row] * bf2f(yn[i]);
}

__global__ __launch_bounds__(256) void k_scatter(
    const void* __restrict__ ei, const unsigned* __restrict__ flag,
    const float* __restrict__ dinv, const unsigned short* __restrict__ y,
    float* __restrict__ out, int E) {
  const int lane = threadIdx.x & 63;
  long long e = ((long long)blockIdx.x * 256 + threadIdx.x) >> 6;
  if (e >= E) return;
  long long s, d;
  if (*flag) {
    const long long* p = (const long long*)ei;
    s = p[e]; d = p[E + e];
  } else {
    const int* p = (const int*)ei;
    s = (long long)p[e]; d = (long long)p[E + e];
  }
  float v = dinv[(int)d] * bf2f(y[s * 64 + lane]);
  atomicAdd(out + d * 64 + lane, v);
}

__global__ __launch_bounds__(256) void k_clip(float4* __restrict__ out, int n4) {
  int i = blockIdx.x * 256 + threadIdx.x;
  if (i >= n4) return;
  float4 v = out[i];
  v.x = fminf(fmaxf(v.x, -50.f), 50.f);
  v.y = fminf(fmaxf(v.y, -50.f), 50.f);
  v.z = fminf(fmaxf(v.z, -50.f), 50.f);
  v.w = fminf(fmaxf(v.w, -50.f), 50.f);
  out[i] = v;
}

// ---------------------------------------------------------------------------
extern "C" void kernel_launch(void* const* d_in, const int* in_sizes, int n_in,
                              void* d_out, int out_size, void* d_ws, size_t ws_size,
                              hipStream_t stream) {
  const float* h      = (const float*)d_in[1];
  const void*  ei_pos = d_in[2];
  const void*  ei_neg = d_in[3];
  const float* gamma  = (const float*)d_in[4];
  const float* beta   = (const float*)d_in[5];
  const float* W_pos  = (const float*)d_in[6];
  const float* b_pos  = (const float*)d_in[7];
  const float* W_neg  = (const float*)d_in[8];
  const float* b_neg  = (const float*)d_in[9];
  const float* Wp     = (const float*)d_in[10];
  const float* bp     = (const float*)d_in[11];
  const float* Wn     = (const float*)d_in[12];
  const float* bn     = (const float*)d_in[13];
  float* out = (float*)d_out;

  const int N = in_sizes[1] / HID;
  const int Ep = in_sizes[2] / 2;
  const int En = in_sizes[3] / 2;
  const int nb = (N + 255) / 256;

  float* ws = (float*)d_ws;
  size_t off = 0;
  auto alloc = [&](size_t nf) {
    float* p = ws + off;
    off = (off + nf + 63) & ~(size_t)63;
    return p;
  };
  // Common arrays (fallback needs only these).
  unsigned short* y_pos = (unsigned short*)alloc((size_t)N * HID / 2);
  unsigned short* y_neg = (unsigned short*)alloc((size_t)N * HID / 2);
  float* dinvp = alloc(N);
  float* dinvn = alloc(N);
  float* Mp    = alloc(64 * 64);
  float* Mn    = alloc(64 * 64);
  float* cvec  = alloc(64);
  unsigned* flag = (unsigned*)alloc(64);
  // Fast-path (CSR) arrays.
  unsigned* deg   = (unsigned*)alloc(2 * (size_t)N);  // [degp|degn] -> cursors
  unsigned* offsp = (unsigned*)alloc(N + 1);
  unsigned* offsn = (unsigned*)alloc(N + 1);
  unsigned* csrp  = (unsigned*)alloc(Ep);
  unsigned* csrn  = (unsigned*)alloc(En);
  unsigned* bsum  = (unsigned*)alloc(2 * (size_t)nb);
  const bool fast = off * sizeof(float) <= ws_size;

  k_detect<<<1, 1024, 0, stream>>>((const unsigned*)ei_pos, flag, 2 * Ep);
  k_prep<<<16, 256, 0, stream>>>(W_pos, W_neg, Wp, Wn, b_pos, b_neg, bp, bn, Mp, Mn, cvec);

  const int eb2 = (int)(((long long)Ep + En + 255) / 256);

  if (fast) {
    hipMemsetAsync(deg, 0, sizeof(unsigned) * 2 * (size_t)N, stream);
    k_degu2<<<eb2, 256, 0, stream>>>(ei_pos, ei_neg, flag, deg, Ep, En, N);
    k_blocksum2<<<2 * nb, 256, 0, stream>>>(deg, bsum, N, nb);
    k_scanp2<<<2, 256, 0, stream>>>(bsum, nb);
    k_offs2<<<2 * nb, 256, 0, stream>>>(deg, offsp, offsn, bsum, dinvp, dinvn,
                                        N, nb, Ep, En);
    k_fill2<<<eb2, 256, 0, stream>>>(ei_pos, ei_neg, flag, deg, csrp, csrn, Ep, En, N);
    k_ln_gemm<<<(N + 63) / 64, 256, 0, stream>>>(h, gamma, beta, Mp, Mn, dinvp, dinvn,
                                                 y_pos, y_neg, N);
    const long long gthreads = (long long)N * 64;
    k_gather<<<(int)((gthreads + 255) / 256), 256, 0, stream>>>(
        offsp, csrp, dinvp, offsn, csrn, dinvn, y_pos, y_neg, cvec, out, N);
  } else {
    hipMemsetAsync(dinvp, 0, sizeof(float) * N, stream);
    hipMemsetAsync(dinvn, 0, sizeof(float) * N, stream);
    k_deg<<<(Ep + 255) / 256, 256, 0, stream>>>(ei_pos, flag, dinvp, Ep);
    k_deg<<<(En + 255) / 256, 256, 0, stream>>>(ei_neg, flag, dinvn, En);
    k_dinv<<<(N + 255) / 256, 256, 0, stream>>>(dinvp, dinvn, N);
    k_ln_gemm<<<(N + 63) / 64, 256, 0, stream>>>(h, gamma, beta, Mp, Mn, dinvp, dinvn,
                                                 y_pos, y_neg, N);
    const long long n = (long long)N * 64;
    k_init_out<<<(int)((n + 255) / 256), 256, 0, stream>>>(y_pos, y_neg, dinvp, dinvn,
                                                           cvec, out, n);
    const long long st = (long long)Ep * 64;
    k_scatter<<<(int)((st + 255) / 256), 256, 0, stream>>>(ei_pos, flag, dinvp, y_pos,
                                                           out, Ep);
    const long long stn = (long long)En * 64;
    k_scatter<<<(int)((stn + 255) / 256), 256, 0, stream>>>(ei_neg, flag, dinvn, y_neg,
                                                            out, En);
    const int n4 = N * 16;
    k_clip<<<(n4 + 255) / 256, 256, 0, stream>>>((float4*)out, n4);
  }
}